// Round 1
// baseline (374.616 us; speedup 1.0000x reference)
//
#include <hip/hip_runtime.h>
#include <cstdint>
#include <cstddef>

// Problem constants
constexpr int DD = 1024;        // D
constexpr int TT = 4096;        // T
constexpr int BB = 4;           // B
constexpr int MM = BB * TT;     // 16384 rows

typedef __bf16 bf16x8 __attribute__((ext_vector_type(8)));
typedef float  f32x4  __attribute__((ext_vector_type(4)));

__device__ __forceinline__ unsigned short f2bf(float f) {
  union { float f; uint32_t u; } c; c.f = f;
  uint32_t r = (c.u + 0x7FFFu + ((c.u >> 16) & 1u)) >> 16;
  return (unsigned short)r;
}
__device__ __forceinline__ float bf2f(unsigned short s) {
  union { uint32_t u; float f; } c; c.u = ((uint32_t)s) << 16;
  return c.f;
}

// async global->LDS 16B per lane; lds_dst must be wave-uniform (HW adds lane*16)
__device__ __forceinline__ void async_ld16(const unsigned short* g, unsigned short* lds_dst) {
  __builtin_amdgcn_global_load_lds(
      (const __attribute__((address_space(1))) void*)g,
      (__attribute__((address_space(3))) void*)lds_dst,
      16, 0, 0);
}

// ---------------------------------------------------------------------------
// Prep: fold time-mix into weights, cast to bf16.
// wkvr layout: [3][1024][1024] row-major (zone = k/v/r), K contiguous.
__global__ void prep_w(const float* __restrict__ Wk, const float* __restrict__ Wv,
                       const float* __restrict__ Wr, const float* __restrict__ Wo,
                       const float* __restrict__ tmk, const float* __restrict__ tmv,
                       const float* __restrict__ tmr,
                       unsigned short* __restrict__ wkvr, unsigned short* __restrict__ wo) {
  int i = blockIdx.x * 256 + threadIdx.x;
  if (i >= DD * DD) return;
  int d = i & (DD - 1);
  wkvr[i]                = f2bf(Wk[i] * tmk[d]);
  wkvr[DD * DD + i]      = f2bf(Wv[i] * tmv[d]);
  wkvr[2 * DD * DD + i]  = f2bf(Wr[i] * tmr[d]);
  wo[i]                  = f2bf(Wo[i]);
}

// bias[e] = sum_d last_x[d]*(1-tm[d])*W[e][d], e in [0,3072). One wave per e.
__global__ void bias_k(const float* __restrict__ Wk, const float* __restrict__ Wv,
                       const float* __restrict__ Wr,
                       const float* __restrict__ tmk, const float* __restrict__ tmv,
                       const float* __restrict__ tmr,
                       const float* __restrict__ last_x, float* __restrict__ bias) {
  int w = (blockIdx.x * blockDim.x + threadIdx.x) >> 6;
  int lane = threadIdx.x & 63;
  if (w >= 3 * DD) return;
  int zone = w >> 10;
  int e = w & (DD - 1);
  const float* W  = (zone == 0) ? Wk  : (zone == 1) ? Wv  : Wr;
  const float* tm = (zone == 0) ? tmk : (zone == 1) ? tmv : tmr;
  float s = 0.f;
  for (int d = lane; d < DD; d += 64)
    s += last_x[d] * (1.0f - tm[d]) * W[(size_t)e * DD + d];
  for (int off = 32; off; off >>= 1) s += __shfl_down(s, off, 64);
  if (lane == 0) bias[w] = s;
}

// x fp32 -> bf16, vectorized
__global__ void cvt_x(const float4* __restrict__ x, ushort4* __restrict__ xb, int n4) {
  int i = blockIdx.x * 256 + threadIdx.x;
  if (i >= n4) return;
  float4 v = x[i];
  ushort4 o;
  o.x = f2bf(v.x); o.y = f2bf(v.y); o.z = f2bf(v.z); o.w = f2bf(v.w);
  xb[i] = o;
}

__global__ void xlast_k(const float* __restrict__ x, float* __restrict__ out_xlast) {
  int i = blockIdx.x * 256 + threadIdx.x;
  if (i >= BB * DD) return;
  int b = i >> 10, d = i & (DD - 1);
  out_xlast[i] = x[((size_t)(b * TT + TT - 1)) * DD + d];
}

// ---------------------------------------------------------------------------
// m97-style bf16 GEMM: C[M,N] = A[M,K] @ B[N,K]^T (+bias[n]).
// 128x128 tile, BK=32, 256 threads (4 waves, 2x2, each wave 64x64 via 4x4 MFMA).
// Writes bf16 (Cbf) or fp32 (Cf).
__global__ void gemm_bt128(const unsigned short* __restrict__ A,
                           const unsigned short* __restrict__ Bw,
                           const float* __restrict__ bias,
                           unsigned short* __restrict__ Cbf,
                           float* __restrict__ Cf,
                           int M, int N, int K) {
  __shared__ unsigned short lA[128 * 32];
  __shared__ unsigned short lB[128 * 32];
  const int tid  = threadIdx.x;
  const int lane = tid & 63;
  const int wave = tid >> 6;
  const int n0 = blockIdx.x * 128;
  const int m0 = blockIdx.y * 128;
  const int wm = (wave >> 1) * 64;
  const int wn = (wave & 1) * 64;

  f32x4 acc[4][4] = {};

  const int fr_row = lane & 15;          // row within 16-tile
  const int fr_kb  = (lane >> 4) * 16;   // byte offset within row (8 bf16)

  for (int k0 = 0; k0 < K; k0 += 32) {
    __syncthreads();  // previous iter's LDS reads done before overwrite
#pragma unroll
    for (int it = 0; it < 2; ++it) {
      int cc  = it * 256 + wave * 64 + lane;
      int row = cc >> 2;
      int col = (cc & 3) * 8;
      async_ld16(A + (size_t)(m0 + row) * K + (k0 + col),
                 lA + (size_t)(it * 256 + wave * 64) * 8);
    }
#pragma unroll
    for (int it = 0; it < 2; ++it) {
      int cc  = it * 256 + wave * 64 + lane;
      int row = cc >> 2;
      int col = (cc & 3) * 8;
      async_ld16(Bw + (size_t)(n0 + row) * K + (k0 + col),
                 lB + (size_t)(it * 256 + wave * 64) * 8);
    }
    __syncthreads();  // staging landed

    bf16x8 af[4], bfr[4];
#pragma unroll
    for (int i = 0; i < 4; ++i) {
      af[i]  = *(const bf16x8*)((const char*)lA + ((wm + i * 16 + fr_row) * 64 + fr_kb));
      bfr[i] = *(const bf16x8*)((const char*)lB + ((wn + i * 16 + fr_row) * 64 + fr_kb));
    }
#pragma unroll
    for (int mi = 0; mi < 4; ++mi)
#pragma unroll
      for (int ni = 0; ni < 4; ++ni)
        acc[mi][ni] = __builtin_amdgcn_mfma_f32_16x16x32_bf16(af[mi], bfr[ni], acc[mi][ni], 0, 0, 0);
  }

  // Epilogue. C/D layout: col = lane&15, row = (lane>>4)*4 + reg.
  const int crow = (lane >> 4) * 4;
  const int ccol = lane & 15;
#pragma unroll
  for (int mi = 0; mi < 4; ++mi) {
#pragma unroll
    for (int ni = 0; ni < 4; ++ni) {
      int gn = n0 + wn + ni * 16 + ccol;
      float bv = bias ? bias[gn] : 0.0f;
#pragma unroll
      for (int r = 0; r < 4; ++r) {
        int gm = m0 + wm + mi * 16 + crow + r;
        float v = acc[mi][ni][r] + bv;
        if (Cf) Cf[(size_t)gm * N + gn] = v;
        else    Cbf[(size_t)gm * N + gn] = f2bf(v);
      }
    }
  }
}

// ---------------------------------------------------------------------------
// Elementwise WKV. kvr: [M][3072] bf16 (k|v|r zones). rwkv: [M][1024] bf16.
// Also emits num/den state outputs for t == T-1 rows.
__global__ void wkv_ew(const unsigned short* __restrict__ kvr,
                       unsigned short* __restrict__ rwkv,
                       const float* __restrict__ time_first,
                       const float* __restrict__ time_decay,
                       const float* __restrict__ last_num,
                       const float* __restrict__ last_den,
                       float* __restrict__ out_num, float* __restrict__ out_den) {
  int idx = blockIdx.x * 256 + threadIdx.x;
  if (idx >= MM * DD) return;
  int m = idx >> 10;
  int d = idx & (DD - 1);
  size_t base = (size_t)m * 3072;
  float kk = bf2f(kvr[base + d]);
  float vv = bf2f(kvr[base + 1024 + d]);
  float rr = bf2f(kvr[base + 2048 + d]);
  float ln = last_num[d], ld = last_den[d];
  float efk = expf(time_first[d] + kk);
  float wkv = (ln + efk * vv) / (ld + efk);
  float sr  = 1.0f / (1.0f + expf(-rr));
  rwkv[idx] = f2bf(sr * wkv);
  if ((m & (TT - 1)) == (TT - 1)) {
    int b = m >> 12;  // m / TT
    float decay = expf(-expf(time_decay[d]));
    float ek = expf(kk);
    out_num[b * DD + d] = decay * ln + ek * vv;
    out_den[b * DD + d] = decay * ld + ek;
  }
}

// ---------------------------------------------------------------------------
extern "C" void kernel_launch(void* const* d_in, const int* in_sizes, int n_in,
                              void* d_out, int out_size, void* d_ws, size_t ws_size,
                              hipStream_t stream) {
  const float* x          = (const float*)d_in[0];
  const float* last_x     = (const float*)d_in[1];
  const float* last_num   = (const float*)d_in[2];
  const float* last_den   = (const float*)d_in[3];
  const float* time_decay = (const float*)d_in[4];
  const float* time_first = (const float*)d_in[5];
  const float* tmk        = (const float*)d_in[6];
  const float* tmv        = (const float*)d_in[7];
  const float* tmr        = (const float*)d_in[8];
  const float* Wk         = (const float*)d_in[9];
  const float* Wv         = (const float*)d_in[10];
  const float* Wr         = (const float*)d_in[11];
  const float* Wo         = (const float*)d_in[12];

  float* out       = (float*)d_out;                  // [MM][DD]
  float* out_xlast = out + (size_t)MM * DD;          // [BB][DD]
  float* out_num   = out_xlast + BB * DD;            // [BB][DD]
  float* out_den   = out_num + BB * DD;              // [BB][DD]

  char* ws = (char*)d_ws;
  unsigned short* xb   = (unsigned short*)ws;                      // 33,554,432 B (also rwkv later)
  unsigned short* wkvr = (unsigned short*)(ws + 33554432);         //  6,291,456 B
  unsigned short* wo   = (unsigned short*)(ws + 39845888);         //  2,097,152 B
  float*          bias = (float*)(ws + 41943040);                  //     12,288 B
  unsigned short* kvr  = (unsigned short*)(ws + 41955328);         // 100,663,296 B -> 142,618,624 total
  unsigned short* rwkv = xb;  // alias: x_bf16 is dead after GEMM1

  prep_w<<<(DD * DD + 255) / 256, 256, 0, stream>>>(Wk, Wv, Wr, Wo, tmk, tmv, tmr, wkvr, wo);
  bias_k<<<(3 * DD * 64 + 255) / 256, 256, 0, stream>>>(Wk, Wv, Wr, tmk, tmv, tmr, last_x, bias);
  cvt_x<<<(MM * DD / 4 + 255) / 256, 256, 0, stream>>>((const float4*)x, (ushort4*)xb, MM * DD / 4);
  xlast_k<<<(BB * DD + 255) / 256, 256, 0, stream>>>(x, out_xlast);

  // KVR = x_bf16 @ wkvr^T + bias : [16384, 3072]
  gemm_bt128<<<dim3(3 * DD / 128, MM / 128), 256, 0, stream>>>(
      xb, wkvr, bias, kvr, nullptr, MM, 3 * DD, DD);

  wkv_ew<<<(MM * DD + 255) / 256, 256, 0, stream>>>(
      kvr, rwkv, time_first, time_decay, last_num, last_den, out_num, out_den);

  // out = rwkv @ wo^T : [16384, 1024]
  gemm_bt128<<<dim3(DD / 128, MM / 128), 256, 0, stream>>>(
      rwkv, wo, nullptr, nullptr, out, MM, DD, DD);
}

// Round 2
// 316.760 us; speedup vs baseline: 1.1826x; 1.1826x over previous
//
#include <hip/hip_runtime.h>
#include <cstdint>
#include <cstddef>

// Problem constants
constexpr int DD = 1024;        // D
constexpr int TT = 4096;        // T
constexpr int BB = 4;           // B
constexpr int MM = BB * TT;     // 16384 rows

typedef __bf16 bf16x8 __attribute__((ext_vector_type(8)));
typedef float  f32x4  __attribute__((ext_vector_type(4)));

__device__ __forceinline__ unsigned short f2bf(float f) {
  union { float f; uint32_t u; } c; c.f = f;
  uint32_t r = (c.u + 0x7FFFu + ((c.u >> 16) & 1u)) >> 16;
  return (unsigned short)r;
}

// async global->LDS 16B per lane; lds_dst must be wave-uniform (HW adds lane*16)
__device__ __forceinline__ void async_ld16(const unsigned short* g, unsigned short* lds_dst) {
  __builtin_amdgcn_global_load_lds(
      (const __attribute__((address_space(1))) void*)g,
      (__attribute__((address_space(3))) void*)lds_dst,
      16, 0, 0);
}

// ---------------------------------------------------------------------------
// Fused weight prep: one wave per (zone, row e). Zones 0..2 = Wk/Wv/Wr
// (scaled by time_mix, bias dot accumulated), zone 3 = Wo (cast only).
__global__ void prep_wb(const float* __restrict__ Wk, const float* __restrict__ Wv,
                        const float* __restrict__ Wr, const float* __restrict__ Wo,
                        const float* __restrict__ tmk, const float* __restrict__ tmv,
                        const float* __restrict__ tmr,
                        const float* __restrict__ last_x,
                        unsigned short* __restrict__ wz,   // [3][1024][1024] bf16
                        unsigned short* __restrict__ wo,   // [1024][1024] bf16
                        float* __restrict__ bias) {        // [3][1024]
  int w = (blockIdx.x * 256 + threadIdx.x) >> 6;
  int lane = threadIdx.x & 63;
  int z = w >> 10;           // 0..3
  int e = w & (DD - 1);
  const float* W  = (z == 0) ? Wk  : (z == 1) ? Wv  : (z == 2) ? Wr : Wo;
  const float* tm = (z == 0) ? tmk : (z == 1) ? tmv : tmr;
  unsigned short* dst = (z < 3) ? (wz + (size_t)z * DD * DD + (size_t)e * DD)
                                : (wo + (size_t)e * DD);
  float s = 0.f;
#pragma unroll
  for (int j = 0; j < 4; ++j) {
    int d = j * 256 + lane * 4;
    float4 wv4 = *(const float4*)(W + (size_t)e * DD + d);
    if (z < 3) {
      float4 t4 = *(const float4*)(tm + d);
      float4 l4 = *(const float4*)(last_x + d);
      s += l4.x * (1.f - t4.x) * wv4.x + l4.y * (1.f - t4.y) * wv4.y +
           l4.z * (1.f - t4.z) * wv4.z + l4.w * (1.f - t4.w) * wv4.w;
      wv4.x *= t4.x; wv4.y *= t4.y; wv4.z *= t4.z; wv4.w *= t4.w;
    }
    ushort4 o;
    o.x = f2bf(wv4.x); o.y = f2bf(wv4.y); o.z = f2bf(wv4.z); o.w = f2bf(wv4.w);
    *(ushort4*)(dst + d) = o;
  }
  if (z < 3) {
    for (int off = 32; off; off >>= 1) s += __shfl_down(s, off, 64);
    if (lane == 0) bias[z * DD + e] = s;
  }
}

// x fp32 -> bf16, vectorized; also emits x[:, T-1, :] (fp32) state output.
__global__ void cvt_x(const float4* __restrict__ x, ushort4* __restrict__ xb,
                      float4* __restrict__ out_xlast) {
  int i = blockIdx.x * 256 + threadIdx.x;   // i < MM*DD/4
  float4 v = x[i];
  ushort4 o;
  o.x = f2bf(v.x); o.y = f2bf(v.y); o.z = f2bf(v.z); o.w = f2bf(v.w);
  xb[i] = o;
  int m = i >> 8;                            // 256 float4 per row
  if ((m & (TT - 1)) == (TT - 1)) {
    int b = m >> 12;
    out_xlast[b * 256 + (i & 255)] = v;
  }
}

// ---------------------------------------------------------------------------
// Fused GEMM1 + WKV: for one (m,n) tile computes k,v,r = x@W{k,v,r}^T + bias,
// applies WKV elementwise in-register, writes only rwkv (bf16).
// Block: 256 thr (4 waves, 2m x 2n). Block tile: M=128, N=64 per zone, 3 zones.
// Also emits num/den state outputs from lanes holding rows t == T-1.
__global__ __launch_bounds__(256, 2) void gemm_kvr(
    const unsigned short* __restrict__ A,     // [16384][1024] bf16
    const unsigned short* __restrict__ Wz,    // [3][1024][1024] bf16
    const float* __restrict__ bias,           // [3][1024]
    const float* __restrict__ time_first, const float* __restrict__ time_decay,
    const float* __restrict__ last_num, const float* __restrict__ last_den,
    unsigned short* __restrict__ rwkv,        // [16384][1024] bf16
    float* __restrict__ out_num, float* __restrict__ out_den) {
  __shared__ unsigned short lA[128 * 32];
  __shared__ unsigned short lB[3][64 * 32];
  const int tid  = threadIdx.x;
  const int lane = tid & 63;
  const int wave = tid >> 6;
  const int n0 = blockIdx.x * 64;    // zone-local col base
  const int m0 = blockIdx.y * 128;
  const int wm = (wave >> 1) * 64;
  const int wn = (wave & 1) * 32;

  f32x4 acc[3][4][2] = {};

  const int fr_row = lane & 15;
  const int fr_kb  = (lane >> 4) * 16;   // byte offset within row (8 bf16)
  const int srow = tid >> 2;             // staging row (0..63)
  const int scol = (tid & 3) * 8;        // staging col (bf16 elems)

  for (int k0 = 0; k0 < DD; k0 += 32) {
    __syncthreads();
#pragma unroll
    for (int it = 0; it < 2; ++it) {
      int cc  = it * 256 + tid;
      int row = cc >> 2;
      async_ld16(A + (size_t)(m0 + row) * DD + (k0 + scol),
                 lA + (size_t)(it * 256 + wave * 64) * 8);
    }
#pragma unroll
    for (int z = 0; z < 3; ++z) {
      async_ld16(Wz + (size_t)z * DD * DD + (size_t)(n0 + srow) * DD + (k0 + scol),
                 lB[z] + (size_t)(wave * 64) * 8);
    }
    __syncthreads();

    bf16x8 af[4], bfr[3][2];
#pragma unroll
    for (int i = 0; i < 4; ++i)
      af[i] = *(const bf16x8*)((const char*)lA + ((wm + i * 16 + fr_row) * 64 + fr_kb));
#pragma unroll
    for (int z = 0; z < 3; ++z)
#pragma unroll
      for (int j = 0; j < 2; ++j)
        bfr[z][j] = *(const bf16x8*)((const char*)lB[z] + ((wn + j * 16 + fr_row) * 64 + fr_kb));

#pragma unroll
    for (int mi = 0; mi < 4; ++mi)
#pragma unroll
      for (int z = 0; z < 3; ++z)
#pragma unroll
        for (int ni = 0; ni < 2; ++ni)
          acc[z][mi][ni] = __builtin_amdgcn_mfma_f32_16x16x32_bf16(
              af[mi], bfr[z][ni], acc[z][mi][ni], 0, 0, 0);
  }

  // Epilogue: WKV in-register. C/D layout: col = lane&15, row = (lane>>4)*4 + reg.
  const int crow = (lane >> 4) * 4;
  const int ccol = lane & 15;
#pragma unroll
  for (int ni = 0; ni < 2; ++ni) {
    int gnz = n0 + wn + ni * 16 + ccol;   // zone-local channel d
    float bk = bias[gnz], bv = bias[DD + gnz], br = bias[2 * DD + gnz];
    float tf = time_first[gnz];
    float ln = last_num[gnz], ld = last_den[gnz];
#pragma unroll
    for (int mi = 0; mi < 4; ++mi) {
#pragma unroll
      for (int r = 0; r < 4; ++r) {
        int gm = m0 + wm + mi * 16 + crow + r;
        float kk = acc[0][mi][ni][r] + bk;
        float vv = acc[1][mi][ni][r] + bv;
        float rr = acc[2][mi][ni][r] + br;
        float efk = __expf(tf + kk);
        float wkv = (ln + efk * vv) / (ld + efk);
        float sr  = 1.0f / (1.0f + __expf(-rr));
        rwkv[(size_t)gm * DD + gnz] = f2bf(sr * wkv);
        if ((gm & (TT - 1)) == (TT - 1)) {
          int b = gm >> 12;
          float dec = __expf(-__expf(time_decay[gnz]));
          float ek  = __expf(kk);
          out_num[b * DD + gnz] = dec * ln + ek * vv;
          out_den[b * DD + gnz] = dec * ld + ek;
        }
      }
    }
  }
}

// ---------------------------------------------------------------------------
// m97-style bf16 GEMM (GEMM2): C[M,N] = A[M,K] @ B[N,K]^T, fp32 out.
__global__ void gemm_bt128(const unsigned short* __restrict__ A,
                           const unsigned short* __restrict__ Bw,
                           float* __restrict__ Cf,
                           int M, int N, int K) {
  __shared__ unsigned short lA[128 * 32];
  __shared__ unsigned short lB[128 * 32];
  const int tid  = threadIdx.x;
  const int lane = tid & 63;
  const int wave = tid >> 6;
  const int n0 = blockIdx.x * 128;
  const int m0 = blockIdx.y * 128;
  const int wm = (wave >> 1) * 64;
  const int wn = (wave & 1) * 64;

  f32x4 acc[4][4] = {};
  const int fr_row = lane & 15;
  const int fr_kb  = (lane >> 4) * 16;

  for (int k0 = 0; k0 < K; k0 += 32) {
    __syncthreads();
#pragma unroll
    for (int it = 0; it < 2; ++it) {
      int cc  = it * 256 + wave * 64 + lane;
      int row = cc >> 2;
      int col = (cc & 3) * 8;
      async_ld16(A + (size_t)(m0 + row) * K + (k0 + col),
                 lA + (size_t)(it * 256 + wave * 64) * 8);
    }
#pragma unroll
    for (int it = 0; it < 2; ++it) {
      int cc  = it * 256 + wave * 64 + lane;
      int row = cc >> 2;
      int col = (cc & 3) * 8;
      async_ld16(Bw + (size_t)(n0 + row) * K + (k0 + col),
                 lB + (size_t)(it * 256 + wave * 64) * 8);
    }
    __syncthreads();

    bf16x8 af[4], bfr[4];
#pragma unroll
    for (int i = 0; i < 4; ++i) {
      af[i]  = *(const bf16x8*)((const char*)lA + ((wm + i * 16 + fr_row) * 64 + fr_kb));
      bfr[i] = *(const bf16x8*)((const char*)lB + ((wn + i * 16 + fr_row) * 64 + fr_kb));
    }
#pragma unroll
    for (int mi = 0; mi < 4; ++mi)
#pragma unroll
      for (int ni = 0; ni < 4; ++ni)
        acc[mi][ni] = __builtin_amdgcn_mfma_f32_16x16x32_bf16(af[mi], bfr[ni], acc[mi][ni], 0, 0, 0);
  }

  const int crow = (lane >> 4) * 4;
  const int ccol = lane & 15;
#pragma unroll
  for (int mi = 0; mi < 4; ++mi) {
#pragma unroll
    for (int ni = 0; ni < 4; ++ni) {
      int gn = n0 + wn + ni * 16 + ccol;
#pragma unroll
      for (int r = 0; r < 4; ++r) {
        int gm = m0 + wm + mi * 16 + crow + r;
        Cf[(size_t)gm * N + gn] = acc[mi][ni][r];
      }
    }
  }
}

// ---------------------------------------------------------------------------
extern "C" void kernel_launch(void* const* d_in, const int* in_sizes, int n_in,
                              void* d_out, int out_size, void* d_ws, size_t ws_size,
                              hipStream_t stream) {
  const float* x          = (const float*)d_in[0];
  const float* last_x     = (const float*)d_in[1];
  const float* last_num   = (const float*)d_in[2];
  const float* last_den   = (const float*)d_in[3];
  const float* time_decay = (const float*)d_in[4];
  const float* time_first = (const float*)d_in[5];
  const float* tmk        = (const float*)d_in[6];
  const float* tmv        = (const float*)d_in[7];
  const float* tmr        = (const float*)d_in[8];
  const float* Wk         = (const float*)d_in[9];
  const float* Wv         = (const float*)d_in[10];
  const float* Wr         = (const float*)d_in[11];
  const float* Wo         = (const float*)d_in[12];

  float* out       = (float*)d_out;                  // [MM][DD]
  float* out_xlast = out + (size_t)MM * DD;          // [BB][DD]
  float* out_num   = out_xlast + BB * DD;            // [BB][DD]
  float* out_den   = out_num + BB * DD;              // [BB][DD]

  char* ws = (char*)d_ws;
  unsigned short* xb   = (unsigned short*)ws;                 // 33,554,432 B
  unsigned short* wz   = (unsigned short*)(ws + 33554432);    //  6,291,456 B
  unsigned short* wo   = (unsigned short*)(ws + 39845888);    //  2,097,152 B
  float*          bias = (float*)(ws + 41943040);             //     12,288 B
  unsigned short* rwkv = (unsigned short*)(ws + 41955328);    // 33,554,432 B (NO alias with xb: fused kernel reads xb while writing rwkv)

  prep_wb<<<(4 * DD * 64) / 256, 256, 0, stream>>>(
      Wk, Wv, Wr, Wo, tmk, tmv, tmr, last_x, wz, wo, bias);
  cvt_x<<<(MM * DD / 4) / 256, 256, 0, stream>>>(
      (const float4*)x, (ushort4*)xb, (float4*)out_xlast);

  // Fused: kvr GEMM + WKV -> rwkv [16384, 1024], plus num/den state rows
  gemm_kvr<<<dim3(DD / 64, MM / 128), 256, 0, stream>>>(
      xb, wz, bias, time_first, time_decay, last_num, last_den,
      rwkv, out_num, out_den);

  // out = rwkv @ wo^T : [16384, 1024]
  gemm_bt128<<<dim3(DD / 128, MM / 128), 256, 0, stream>>>(
      rwkv, wo, out, MM, DD, DD);
}

// Round 3
// 301.069 us; speedup vs baseline: 1.2443x; 1.0521x over previous
//
#include <hip/hip_runtime.h>
#include <cstdint>
#include <cstddef>

// Problem constants
constexpr int DD = 1024;        // D
constexpr int TT = 4096;        // T
constexpr int BB = 4;           // B
constexpr int MM = BB * TT;     // 16384 rows

typedef __bf16 bf16x8 __attribute__((ext_vector_type(8)));
typedef float  f32x4  __attribute__((ext_vector_type(4)));

__device__ __forceinline__ unsigned short f2bf(float f) {
  union { float f; uint32_t u; } c; c.f = f;
  uint32_t r = (c.u + 0x7FFFu + ((c.u >> 16) & 1u)) >> 16;
  return (unsigned short)r;
}

__device__ __forceinline__ float fast_rcp(float x) {
  return __builtin_amdgcn_rcpf(x);
}

// async global->LDS 16B per lane; lds_dst must be wave-uniform (HW adds lane*16)
__device__ __forceinline__ void async_ld16(const unsigned short* g, unsigned short* lds_dst) {
  __builtin_amdgcn_global_load_lds(
      (const __attribute__((address_space(1))) void*)g,
      (__attribute__((address_space(3))) void*)lds_dst,
      16, 0, 0);
}

// ---------------------------------------------------------------------------
// Merged prep: blocks [0,1024) fold time-mix into weights (wave per row) and
// accumulate bias dots; blocks [1024, 1024+16384) convert x to bf16 and emit
// x[:, T-1, :].
__global__ void prep_all(const float* __restrict__ Wk, const float* __restrict__ Wv,
                         const float* __restrict__ Wr, const float* __restrict__ Wo,
                         const float* __restrict__ tmk, const float* __restrict__ tmv,
                         const float* __restrict__ tmr,
                         const float* __restrict__ last_x,
                         const float4* __restrict__ x,
                         unsigned short* __restrict__ wz,   // [3][1024][1024] bf16
                         unsigned short* __restrict__ wo,   // [1024][1024] bf16
                         float* __restrict__ bias,          // [3][1024]
                         ushort4* __restrict__ xb,          // [16384][1024] bf16
                         float4* __restrict__ out_xlast) {
  if (blockIdx.x < 1024) {
    int w = (blockIdx.x * 256 + threadIdx.x) >> 6;   // 0..4095
    int lane = threadIdx.x & 63;
    int z = w >> 10;           // 0..3
    int e = w & (DD - 1);
    const float* W  = (z == 0) ? Wk  : (z == 1) ? Wv  : (z == 2) ? Wr : Wo;
    const float* tm = (z == 0) ? tmk : (z == 1) ? tmv : tmr;
    unsigned short* dst = (z < 3) ? (wz + (size_t)z * DD * DD + (size_t)e * DD)
                                  : (wo + (size_t)e * DD);
    float s = 0.f;
#pragma unroll
    for (int j = 0; j < 4; ++j) {
      int d = j * 256 + lane * 4;
      float4 wv4 = *(const float4*)(W + (size_t)e * DD + d);
      if (z < 3) {
        float4 t4 = *(const float4*)(tm + d);
        float4 l4 = *(const float4*)(last_x + d);
        s += l4.x * (1.f - t4.x) * wv4.x + l4.y * (1.f - t4.y) * wv4.y +
             l4.z * (1.f - t4.z) * wv4.z + l4.w * (1.f - t4.w) * wv4.w;
        wv4.x *= t4.x; wv4.y *= t4.y; wv4.z *= t4.z; wv4.w *= t4.w;
      }
      ushort4 o;
      o.x = f2bf(wv4.x); o.y = f2bf(wv4.y); o.z = f2bf(wv4.z); o.w = f2bf(wv4.w);
      *(ushort4*)(dst + d) = o;
    }
    if (z < 3) {
      for (int off = 32; off; off >>= 1) s += __shfl_down(s, off, 64);
      if (lane == 0) bias[z * DD + e] = s;
    }
  } else {
    int i = (blockIdx.x - 1024) * 256 + threadIdx.x;  // < MM*DD/4
    float4 v = x[i];
    ushort4 o;
    o.x = f2bf(v.x); o.y = f2bf(v.y); o.z = f2bf(v.z); o.w = f2bf(v.w);
    xb[i] = o;
    int m = i >> 8;                                    // 256 float4 per row
    if ((m & (TT - 1)) == (TT - 1)) {
      int b = m >> 12;
      out_xlast[b * 256 + (i & 255)] = v;
    }
  }
}

// ---------------------------------------------------------------------------
// Fused GEMM1 + WKV, two-panel BK=64 (halved barrier count).
// Block: 256 thr (4 waves, 2m x 2n). Tile: M=128, N=64 per zone, 3 zones.
__global__ __launch_bounds__(256, 2) void gemm_kvr(
    const unsigned short* __restrict__ A,     // [16384][1024] bf16
    const unsigned short* __restrict__ Wz,    // [3][1024][1024] bf16
    const float* __restrict__ bias,           // [3][1024]
    const float* __restrict__ time_first, const float* __restrict__ time_decay,
    const float* __restrict__ last_num, const float* __restrict__ last_den,
    unsigned short* __restrict__ rwkv,        // [16384][1024] bf16
    float* __restrict__ out_num, float* __restrict__ out_den) {
  __shared__ unsigned short lA[2][128 * 32];
  __shared__ unsigned short lB[2][3][64 * 32];
  const int tid  = threadIdx.x;
  const int lane = tid & 63;
  const int wave = tid >> 6;
  const int n0 = blockIdx.x * 64;    // zone-local col base
  const int m0 = blockIdx.y * 128;
  const int wm = (wave >> 1) * 64;
  const int wn = (wave & 1) * 32;

  f32x4 acc[3][4][2] = {};

  const int fr_row = lane & 15;
  const int fr_kb  = (lane >> 4) * 16;   // byte offset within row (8 bf16)
  const int srow = tid >> 2;             // staging row (0..63)
  const int scol = (tid & 3) * 8;        // staging col (bf16 elems)

  for (int k0 = 0; k0 < DD; k0 += 64) {
    __syncthreads();
#pragma unroll
    for (int h = 0; h < 2; ++h) {
      int kk = k0 + h * 32;
#pragma unroll
      for (int it = 0; it < 2; ++it) {
        int cc  = it * 256 + tid;
        int row = cc >> 2;
        async_ld16(A + (size_t)(m0 + row) * DD + (kk + scol),
                   lA[h] + (size_t)(it * 256 + wave * 64) * 8);
      }
#pragma unroll
      for (int z = 0; z < 3; ++z) {
        async_ld16(Wz + (size_t)z * DD * DD + (size_t)(n0 + srow) * DD + (kk + scol),
                   lB[h][z] + (size_t)(wave * 64) * 8);
      }
    }
    __syncthreads();

#pragma unroll
    for (int h = 0; h < 2; ++h) {
      bf16x8 af[4], bfr[3][2];
#pragma unroll
      for (int i = 0; i < 4; ++i)
        af[i] = *(const bf16x8*)((const char*)lA[h] + ((wm + i * 16 + fr_row) * 64 + fr_kb));
#pragma unroll
      for (int z = 0; z < 3; ++z)
#pragma unroll
        for (int j = 0; j < 2; ++j)
          bfr[z][j] = *(const bf16x8*)((const char*)lB[h][z] + ((wn + j * 16 + fr_row) * 64 + fr_kb));

#pragma unroll
      for (int mi = 0; mi < 4; ++mi)
#pragma unroll
        for (int z = 0; z < 3; ++z)
#pragma unroll
          for (int ni = 0; ni < 2; ++ni)
            acc[z][mi][ni] = __builtin_amdgcn_mfma_f32_16x16x32_bf16(
                af[mi], bfr[z][ni], acc[z][mi][ni], 0, 0, 0);
    }
  }

  // Epilogue: WKV in-register. C/D layout: col = lane&15, row = (lane>>4)*4 + reg.
  const int crow = (lane >> 4) * 4;
  const int ccol = lane & 15;
#pragma unroll
  for (int ni = 0; ni < 2; ++ni) {
    int gnz = n0 + wn + ni * 16 + ccol;   // zone-local channel d
    float bk = bias[gnz], bv = bias[DD + gnz], br = bias[2 * DD + gnz];
    float tf = time_first[gnz];
    float ln = last_num[gnz], ld = last_den[gnz];
#pragma unroll
    for (int mi = 0; mi < 4; ++mi) {
#pragma unroll
      for (int r = 0; r < 4; ++r) {
        int gm = m0 + wm + mi * 16 + crow + r;
        float kk = acc[0][mi][ni][r] + bk;
        float vv = acc[1][mi][ni][r] + bv;
        float rr = acc[2][mi][ni][r] + br;
        float efk = __expf(tf + kk);
        float wkv = (ln + efk * vv) * fast_rcp(ld + efk);
        float sr  = fast_rcp(1.0f + __expf(-rr));
        rwkv[(size_t)gm * DD + gnz] = f2bf(sr * wkv);
        if ((gm & (TT - 1)) == (TT - 1)) {
          int b = gm >> 12;
          float dec = __expf(-__expf(time_decay[gnz]));
          float ek  = __expf(kk);
          out_num[b * DD + gnz] = dec * ln + ek * vv;
          out_den[b * DD + gnz] = dec * ld + ek;
        }
      }
    }
  }
}

// ---------------------------------------------------------------------------
// GEMM2: C[M,N] = A[M,K] @ B[N,K]^T, fp32 out. Two-panel BK=64.
__global__ void gemm_bt128(const unsigned short* __restrict__ A,
                           const unsigned short* __restrict__ Bw,
                           float* __restrict__ Cf,
                           int M, int N, int K) {
  __shared__ unsigned short lA[2][128 * 32];
  __shared__ unsigned short lB[2][128 * 32];
  const int tid  = threadIdx.x;
  const int lane = tid & 63;
  const int wave = tid >> 6;
  const int n0 = blockIdx.x * 128;
  const int m0 = blockIdx.y * 128;
  const int wm = (wave >> 1) * 64;
  const int wn = (wave & 1) * 64;

  f32x4 acc[4][4] = {};
  const int fr_row = lane & 15;
  const int fr_kb  = (lane >> 4) * 16;
  const int scol = (tid & 3) * 8;

  for (int k0 = 0; k0 < K; k0 += 64) {
    __syncthreads();
#pragma unroll
    for (int h = 0; h < 2; ++h) {
      int kk = k0 + h * 32;
#pragma unroll
      for (int it = 0; it < 2; ++it) {
        int cc  = it * 256 + tid;
        int row = cc >> 2;
        async_ld16(A + (size_t)(m0 + row) * K + (kk + scol),
                   lA[h] + (size_t)(it * 256 + wave * 64) * 8);
      }
#pragma unroll
      for (int it = 0; it < 2; ++it) {
        int cc  = it * 256 + tid;
        int row = cc >> 2;
        async_ld16(Bw + (size_t)(n0 + row) * K + (kk + scol),
                   lB[h] + (size_t)(it * 256 + wave * 64) * 8);
      }
    }
    __syncthreads();

#pragma unroll
    for (int h = 0; h < 2; ++h) {
      bf16x8 af[4], bfr[4];
#pragma unroll
      for (int i = 0; i < 4; ++i) {
        af[i]  = *(const bf16x8*)((const char*)lA[h] + ((wm + i * 16 + fr_row) * 64 + fr_kb));
        bfr[i] = *(const bf16x8*)((const char*)lB[h] + ((wn + i * 16 + fr_row) * 64 + fr_kb));
      }
#pragma unroll
      for (int mi = 0; mi < 4; ++mi)
#pragma unroll
        for (int ni = 0; ni < 4; ++ni)
          acc[mi][ni] = __builtin_amdgcn_mfma_f32_16x16x32_bf16(af[mi], bfr[ni], acc[mi][ni], 0, 0, 0);
    }
  }

  const int crow = (lane >> 4) * 4;
  const int ccol = lane & 15;
#pragma unroll
  for (int mi = 0; mi < 4; ++mi) {
#pragma unroll
    for (int ni = 0; ni < 4; ++ni) {
      int gn = n0 + wn + ni * 16 + ccol;
#pragma unroll
      for (int r = 0; r < 4; ++r) {
        int gm = m0 + wm + mi * 16 + crow + r;
        Cf[(size_t)gm * N + gn] = acc[mi][ni][r];
      }
    }
  }
}

// ---------------------------------------------------------------------------
extern "C" void kernel_launch(void* const* d_in, const int* in_sizes, int n_in,
                              void* d_out, int out_size, void* d_ws, size_t ws_size,
                              hipStream_t stream) {
  const float* x          = (const float*)d_in[0];
  const float* last_x     = (const float*)d_in[1];
  const float* last_num   = (const float*)d_in[2];
  const float* last_den   = (const float*)d_in[3];
  const float* time_decay = (const float*)d_in[4];
  const float* time_first = (const float*)d_in[5];
  const float* tmk        = (const float*)d_in[6];
  const float* tmv        = (const float*)d_in[7];
  const float* tmr        = (const float*)d_in[8];
  const float* Wk         = (const float*)d_in[9];
  const float* Wv         = (const float*)d_in[10];
  const float* Wr         = (const float*)d_in[11];
  const float* Wo         = (const float*)d_in[12];

  float* out       = (float*)d_out;                  // [MM][DD]
  float* out_xlast = out + (size_t)MM * DD;          // [BB][DD]
  float* out_num   = out_xlast + BB * DD;            // [BB][DD]
  float* out_den   = out_num + BB * DD;              // [BB][DD]

  char* ws = (char*)d_ws;
  unsigned short* xb   = (unsigned short*)ws;                 // 33,554,432 B
  unsigned short* wz   = (unsigned short*)(ws + 33554432);    //  6,291,456 B
  unsigned short* wo   = (unsigned short*)(ws + 39845888);    //  2,097,152 B
  float*          bias = (float*)(ws + 41943040);             //     12,288 B
  unsigned short* rwkv = (unsigned short*)(ws + 41955328);    // 33,554,432 B (no alias with xb: all n-blocks read same A rows)

  prep_all<<<1024 + MM * DD / 4 / 256, 256, 0, stream>>>(
      Wk, Wv, Wr, Wo, tmk, tmv, tmr, last_x, (const float4*)x,
      wz, wo, bias, (ushort4*)xb, (float4*)out_xlast);

  // Fused: kvr GEMM + WKV -> rwkv [16384, 1024], plus num/den state rows
  gemm_kvr<<<dim3(DD / 64, MM / 128), 256, 0, stream>>>(
      xb, wz, bias, time_first, time_decay, last_num, last_den,
      rwkv, out_num, out_den);

  // out = rwkv @ wo^T : [16384, 1024]
  gemm_bt128<<<dim3(DD / 128, MM / 128), 256, 0, stream>>>(
      rwkv, wo, out, MM, DD, DD);
}